// Round 1
// baseline (398.030 us; speedup 1.0000x reference)
//
#include <hip/hip_runtime.h>

#define NN 50000
#define NE 640000
#define HID 128

// ---- workspace layout (bytes) ----
// agg   f32 [NN*HID]            @ 0          25,600,000
// nf16  bf16[NN*HID]            @ 25600000   12,800,000
// W1p   bf16[128*320]           @ 38400000       81,920
// W2p   bf16[128*128]           @ +81920         32,768
// U1p   bf16[128*288]           @ +32768         73,728
// U2p   bf16[128*128]           @ +73728         32,768
// total ~38.7 MB

typedef __attribute__((ext_vector_type(8))) short bf8;  // 8 bf16 = 16B
typedef __attribute__((ext_vector_type(4))) float f4;
typedef __attribute__((ext_vector_type(4))) short s4;

#define MFMA(a, b, c) __builtin_amdgcn_mfma_f32_16x16x32_bf16(a, b, c, 0, 0, 0)

__device__ __forceinline__ short f2bf(float f) {
    union { float f; unsigned u; } v; v.f = f;
    unsigned r = v.u + 0x7FFFu + ((v.u >> 16) & 1u);
    return (short)(r >> 16);
}

// ---------- pre-kernels ----------
__global__ void pack_weights_kernel(const float* __restrict__ mW1, const float* __restrict__ mW2,
                                    const float* __restrict__ uW1, const float* __restrict__ uW2,
                                    short* __restrict__ W1p, short* __restrict__ W2p,
                                    short* __restrict__ U1p, short* __restrict__ U2p) {
    const int stride = gridDim.x * blockDim.x;
    const int idx = blockIdx.x * blockDim.x + threadIdx.x;
    // W1p[n][k] = mW1[k][n], K padded 290 -> 320
    for (int t = idx; t < 128 * 320; t += stride) {
        int n = t / 320, k = t % 320;
        W1p[t] = (k < 290) ? f2bf(mW1[k * 128 + n]) : (short)0;
    }
    for (int t = idx; t < 128 * 128; t += stride)
        W2p[t] = f2bf(mW2[(t % 128) * 128 + (t / 128)]);
    // U1p[n][k] = uW1[k][n], K padded 257 -> 288
    for (int t = idx; t < 128 * 288; t += stride) {
        int n = t / 288, k = t % 288;
        U1p[t] = (k < 257) ? f2bf(uW1[k * 128 + n]) : (short)0;
    }
    for (int t = idx; t < 128 * 128; t += stride)
        U2p[t] = f2bf(uW2[(t % 128) * 128 + (t / 128)]);
}

__global__ void cvt_nf_kernel(const float* __restrict__ in, short* __restrict__ out, int n4) {
    const int stride = gridDim.x * blockDim.x;
    for (int t = blockIdx.x * blockDim.x + threadIdx.x; t < n4; t += stride) {
        f4 v = ((const f4*)in)[t];
        s4 s = { f2bf(v[0]), f2bf(v[1]), f2bf(v[2]), f2bf(v[3]) };
        ((s4*)out)[t] = s;
    }
}

// ---------- edge kernel: message MLP + atomic scatter ----------
// tile = 64 edges x 128 out, K1 = 320 (128 src nf | 128 dst nf | 32 ef | cs,cd,30x0)
__global__ __launch_bounds__(256, 2)
void edge_kernel(const short* __restrict__ nf16, const int* __restrict__ ei,
                 const float* __restrict__ ef, const float* __restrict__ coord,
                 const short* __restrict__ W1p, const float* __restrict__ mb1,
                 const short* __restrict__ W2p, const float* __restrict__ mb2,
                 float* __restrict__ agg) {
    constexpr int K1 = 320, LDA = 328, LDH = 136;
    __shared__ short A[64 * LDA];
    __shared__ short H[64 * LDH];
    __shared__ int sdst[64];

    const int tid = threadIdx.x;
    const int ebase = blockIdx.x * 64;

    // ---- stage A-tile: 4 threads per edge-row ----
    {
        const int r = tid >> 2, q = tid & 3;
        const int e = ebase + r;
        const int s = ei[e];
        const int d = ei[NE + e];
        if (q == 0) sdst[r] = d;
        short* Ar = A + r * LDA;
        const short* ps = nf16 + (long)s * HID + q * 32;
        const short* pd = nf16 + (long)d * HID + q * 32;
#pragma unroll
        for (int j = 0; j < 4; ++j) {
            *(bf8*)(Ar + q * 32 + j * 8) = *(const bf8*)(ps + j * 8);
            *(bf8*)(Ar + 128 + q * 32 + j * 8) = *(const bf8*)(pd + j * 8);
        }
        const float* pe = ef + (long)e * 32 + q * 8;
        f4 v0 = *(const f4*)pe, v1 = *(const f4*)(pe + 4);
        bf8 w = { f2bf(v0[0]), f2bf(v0[1]), f2bf(v0[2]), f2bf(v0[3]),
                  f2bf(v1[0]), f2bf(v1[1]), f2bf(v1[2]), f2bf(v1[3]) };
        *(bf8*)(Ar + 256 + q * 8) = w;
        bf8 z = {};
        *(bf8*)(Ar + 288 + q * 8) = z;
        if (q == 0) { Ar[288] = f2bf(coord[s]); Ar[289] = f2bf(coord[d]); }
    }
    __syncthreads();

    const int lane = tid & 63, wv = tid >> 6;
    const int g = lane >> 4, i16 = lane & 15, wc = wv * 32;

    // ---- layer 1: [64,320] @ [320,128] ----
    f4 acc[4][2] = {};
#pragma unroll
    for (int ks = 0; ks < K1 / 32; ++ks) {
        const int kb = ks * 32 + g * 8;
        bf8 b0 = *(const bf8*)(W1p + (wc + i16) * K1 + kb);
        bf8 b1 = *(const bf8*)(W1p + (wc + 16 + i16) * K1 + kb);
#pragma unroll
        for (int m = 0; m < 4; ++m) {
            bf8 a = *(const bf8*)(A + (m * 16 + i16) * LDA + kb);
            acc[m][0] = MFMA(a, b0, acc[m][0]);
            acc[m][1] = MFMA(a, b1, acc[m][1]);
        }
    }
    // silu -> H (bf16)
    {
        const float c0 = mb1[wc + i16], c1 = mb1[wc + 16 + i16];
#pragma unroll
        for (int m = 0; m < 4; ++m)
#pragma unroll
            for (int n = 0; n < 2; ++n)
#pragma unroll
                for (int i = 0; i < 4; ++i) {
                    const int row = m * 16 + g * 4 + i;
                    const int col = wc + n * 16 + i16;
                    float x = acc[m][n][i] + (n ? c1 : c0);
                    float h = x / (1.f + __expf(-x));
                    H[row * LDH + col] = f2bf(h);
                }
    }
    __syncthreads();

    // ---- layer 2: [64,128] @ [128,128] ----
    f4 acc2[4][2] = {};
#pragma unroll
    for (int ks = 0; ks < 4; ++ks) {
        const int kb = ks * 32 + g * 8;
        bf8 b0 = *(const bf8*)(W2p + (wc + i16) * 128 + kb);
        bf8 b1 = *(const bf8*)(W2p + (wc + 16 + i16) * 128 + kb);
#pragma unroll
        for (int m = 0; m < 4; ++m) {
            bf8 a = *(const bf8*)(H + (m * 16 + i16) * LDH + kb);
            acc2[m][0] = MFMA(a, b0, acc2[m][0]);
            acc2[m][1] = MFMA(a, b1, acc2[m][1]);
        }
    }
    // scatter messages
    {
        const float c0 = mb2[wc + i16], c1 = mb2[wc + 16 + i16];
#pragma unroll
        for (int m = 0; m < 4; ++m)
#pragma unroll
            for (int n = 0; n < 2; ++n)
#pragma unroll
                for (int i = 0; i < 4; ++i) {
                    const int row = m * 16 + g * 4 + i;
                    const int col = wc + n * 16 + i16;
                    float v = acc2[m][n][i] + (n ? c1 : c0);
                    atomicAdd(agg + (long)sdst[row] * HID + col, v);
                }
    }
}

// ---------- node kernel: update MLP + residual + LayerNorm ----------
// tile = 64 nodes, K1 = 288 (128 nf | 128 agg | coord, 31x0)
__global__ __launch_bounds__(256, 2)
void node_kernel(const float* __restrict__ nf, const short* __restrict__ nf16,
                 const float* __restrict__ agg, const float* __restrict__ coord,
                 const short* __restrict__ U1p, const float* __restrict__ ub1,
                 const short* __restrict__ U2p, const float* __restrict__ ub2,
                 const float* __restrict__ gamma, const float* __restrict__ beta,
                 float* __restrict__ out) {
    constexpr int K1 = 288, LDA = 296, LDH = 136, LDX = 132;
    __shared__ short A[64 * LDA];   // later aliased as X (f32 [64][132] = 33792B <= 37888B)
    __shared__ short H[64 * LDH];
    float* X = (float*)A;

    const int tid = threadIdx.x;
    const int nbase = blockIdx.x * 64;

    // ---- stage A-tile ----
    {
        const int r = tid >> 2, q = tid & 3;
        const int node = nbase + r;
        short* Ar = A + r * LDA;
        bf8 z = {};
        if (node < NN) {
            const short* pn = nf16 + (long)node * HID + q * 32;
#pragma unroll
            for (int j = 0; j < 4; ++j)
                *(bf8*)(Ar + q * 32 + j * 8) = *(const bf8*)(pn + j * 8);
            const float* pa = agg + (long)node * HID + q * 32;
#pragma unroll
            for (int j = 0; j < 4; ++j) {
                f4 v0 = *(const f4*)(pa + j * 8);
                f4 v1 = *(const f4*)(pa + j * 8 + 4);
                bf8 w = { f2bf(v0[0]), f2bf(v0[1]), f2bf(v0[2]), f2bf(v0[3]),
                          f2bf(v1[0]), f2bf(v1[1]), f2bf(v1[2]), f2bf(v1[3]) };
                *(bf8*)(Ar + 128 + q * 32 + j * 8) = w;
            }
            *(bf8*)(Ar + 256 + q * 8) = z;
            if (q == 0) Ar[256] = f2bf(coord[node]);
        } else {
#pragma unroll
            for (int j = 0; j < 4; ++j) {
                *(bf8*)(Ar + q * 32 + j * 8) = z;
                *(bf8*)(Ar + 128 + q * 32 + j * 8) = z;
            }
            *(bf8*)(Ar + 256 + q * 8) = z;
        }
    }
    __syncthreads();

    const int lane = tid & 63, wv = tid >> 6;
    const int g = lane >> 4, i16 = lane & 15, wc = wv * 32;

    f4 acc[4][2] = {};
#pragma unroll
    for (int ks = 0; ks < K1 / 32; ++ks) {
        const int kb = ks * 32 + g * 8;
        bf8 b0 = *(const bf8*)(U1p + (wc + i16) * K1 + kb);
        bf8 b1 = *(const bf8*)(U1p + (wc + 16 + i16) * K1 + kb);
#pragma unroll
        for (int m = 0; m < 4; ++m) {
            bf8 a = *(const bf8*)(A + (m * 16 + i16) * LDA + kb);
            acc[m][0] = MFMA(a, b0, acc[m][0]);
            acc[m][1] = MFMA(a, b1, acc[m][1]);
        }
    }
    {
        const float c0 = ub1[wc + i16], c1 = ub1[wc + 16 + i16];
#pragma unroll
        for (int m = 0; m < 4; ++m)
#pragma unroll
            for (int n = 0; n < 2; ++n)
#pragma unroll
                for (int i = 0; i < 4; ++i) {
                    const int row = m * 16 + g * 4 + i;
                    const int col = wc + n * 16 + i16;
                    float x = acc[m][n][i] + (n ? c1 : c0);
                    float h = x / (1.f + __expf(-x));
                    H[row * LDH + col] = f2bf(h);
                }
    }
    __syncthreads();

    f4 acc2[4][2] = {};
#pragma unroll
    for (int ks = 0; ks < 4; ++ks) {
        const int kb = ks * 32 + g * 8;
        bf8 b0 = *(const bf8*)(U2p + (wc + i16) * 128 + kb);
        bf8 b1 = *(const bf8*)(U2p + (wc + 16 + i16) * 128 + kb);
#pragma unroll
        for (int m = 0; m < 4; ++m) {
            bf8 a = *(const bf8*)(H + (m * 16 + i16) * LDH + kb);
            acc2[m][0] = MFMA(a, b0, acc2[m][0]);
            acc2[m][1] = MFMA(a, b1, acc2[m][1]);
        }
    }
    // X = nf + upd  (aliases A: all A reads finished before the H->K2 sync)
    {
        const float c0 = ub2[wc + i16], c1 = ub2[wc + 16 + i16];
#pragma unroll
        for (int m = 0; m < 4; ++m)
#pragma unroll
            for (int n = 0; n < 2; ++n)
#pragma unroll
                for (int i = 0; i < 4; ++i) {
                    const int row = m * 16 + g * 4 + i;
                    const int node = nbase + row;
                    const int col = wc + n * 16 + i16;
                    float v = acc2[m][n][i] + (n ? c1 : c0);
                    float base = (node < NN) ? nf[(long)node * HID + col] : 0.f;
                    X[row * LDX + col] = base + v;
                }
    }
    __syncthreads();

    // LayerNorm: 4 threads per row
    {
        const int r = tid >> 2, q = tid & 3;
        const int node = nbase + r;
        float s = 0.f;
#pragma unroll
        for (int j = 0; j < 32; ++j) s += X[r * LDX + q * 32 + j];
        s += __shfl_xor(s, 1);
        s += __shfl_xor(s, 2);
        const float mu = s * (1.f / 128.f);
        float vv = 0.f;
#pragma unroll
        for (int j = 0; j < 32; ++j) {
            float d = X[r * LDX + q * 32 + j] - mu;
            vv += d * d;
        }
        vv += __shfl_xor(vv, 1);
        vv += __shfl_xor(vv, 2);
        const float rstd = rsqrtf(vv * (1.f / 128.f) + 1e-5f);
        if (node < NN) {
#pragma unroll
            for (int j = 0; j < 32; ++j) {
                const int c = q * 32 + j;
                out[(long)node * HID + c] = (X[r * LDX + c] - mu) * rstd * gamma[c] + beta[c];
            }
        }
    }
}

extern "C" void kernel_launch(void* const* d_in, const int* in_sizes, int n_in,
                              void* d_out, int out_size, void* d_ws, size_t ws_size,
                              hipStream_t stream) {
    const float* nf    = (const float*)d_in[0];
    const int*   ei    = (const int*)d_in[1];
    const float* ef    = (const float*)d_in[2];
    const float* coord = (const float*)d_in[3];
    const float* mW1 = (const float*)d_in[4];
    const float* mb1 = (const float*)d_in[5];
    const float* mW2 = (const float*)d_in[6];
    const float* mb2 = (const float*)d_in[7];
    const float* uW1 = (const float*)d_in[8];
    const float* ub1 = (const float*)d_in[9];
    const float* uW2 = (const float*)d_in[10];
    const float* ub2 = (const float*)d_in[11];
    const float* gamma = (const float*)d_in[12];
    const float* beta  = (const float*)d_in[13];
    float* out = (float*)d_out;

    char* ws = (char*)d_ws;
    float* agg  = (float*)ws;                          // 25,600,000 B
    short* nf16 = (short*)(ws + 25600000);             // 12,800,000 B
    short* W1p  = (short*)(ws + 38400000);
    short* W2p  = W1p + 128 * 320;
    short* U1p  = W2p + 128 * 128;
    short* U2p  = U1p + 128 * 288;

    hipMemsetAsync(agg, 0, (size_t)NN * HID * sizeof(float), stream);
    pack_weights_kernel<<<64, 256, 0, stream>>>(mW1, mW2, uW1, uW2, W1p, W2p, U1p, U2p);
    cvt_nf_kernel<<<1024, 256, 0, stream>>>(nf, nf16, NN * HID / 4);
    edge_kernel<<<NE / 64, 256, 0, stream>>>(nf16, ei, ef, coord, W1p, mb1, W2p, mb2, agg);
    node_kernel<<<(NN + 63) / 64, 256, 0, stream>>>(nf, nf16, agg, coord,
                                                    U1p, ub1, U2p, ub2, gamma, beta, out);
}

// Round 2
// 352.422 us; speedup vs baseline: 1.1294x; 1.1294x over previous
//
#include <hip/hip_runtime.h>

#define NN 50000
#define NE 640000
#define HID 128

// ---- workspace layout (bytes) ----
// agg   f32 [NN*HID]            @ 0            25,600,000
// nf16  bf16[NN*HID]            @ 25,600,000   12,800,000
// W1p   bf16[128*320]           @ 38,400,000       81,920
// W2p   bf16[128*128]           @ 38,481,920       32,768
// U1p   bf16[128*288]           @ 38,514,688       73,728
// U2p   bf16[128*128]           @ 38,588,416       32,768
// hist  int[50000]              @ 38,621,184      200,000
// off   int[50001]              @ 38,821,184      200,004
// pos   int[50000]              @ 39,021,188      200,000
// csum  int[256]                @ 39,221,188        1,024
// perm  int[640000]             @ 39,222,212    2,560,000
// total ~41.8 MB

typedef __attribute__((ext_vector_type(8))) short bf8;  // 8 bf16 = 16B
typedef __attribute__((ext_vector_type(4))) float f4;
typedef __attribute__((ext_vector_type(4))) short s4;

#define MFMA(a, b, c) __builtin_amdgcn_mfma_f32_16x16x32_bf16(a, b, c, 0, 0, 0)

__device__ __forceinline__ short f2bf(float f) {
    union { float f; unsigned u; } v; v.f = f;
    unsigned r = v.u + 0x7FFFu + ((v.u >> 16) & 1u);
    return (short)(r >> 16);
}

// ---------- pre-kernels ----------
__global__ void pack_weights_kernel(const float* __restrict__ mW1, const float* __restrict__ mW2,
                                    const float* __restrict__ uW1, const float* __restrict__ uW2,
                                    short* __restrict__ W1p, short* __restrict__ W2p,
                                    short* __restrict__ U1p, short* __restrict__ U2p) {
    const int stride = gridDim.x * blockDim.x;
    const int idx = blockIdx.x * blockDim.x + threadIdx.x;
    for (int t = idx; t < 128 * 320; t += stride) {
        int n = t / 320, k = t % 320;
        W1p[t] = (k < 290) ? f2bf(mW1[k * 128 + n]) : (short)0;
    }
    for (int t = idx; t < 128 * 128; t += stride)
        W2p[t] = f2bf(mW2[(t % 128) * 128 + (t / 128)]);
    for (int t = idx; t < 128 * 288; t += stride) {
        int n = t / 288, k = t % 288;
        U1p[t] = (k < 257) ? f2bf(uW1[k * 128 + n]) : (short)0;
    }
    for (int t = idx; t < 128 * 128; t += stride)
        U2p[t] = f2bf(uW2[(t % 128) * 128 + (t / 128)]);
}

__global__ void cvt_nf_kernel(const float* __restrict__ in, short* __restrict__ out, int n4) {
    const int stride = gridDim.x * blockDim.x;
    for (int t = blockIdx.x * blockDim.x + threadIdx.x; t < n4; t += stride) {
        f4 v = ((const f4*)in)[t];
        s4 s = { f2bf(v[0]), f2bf(v[1]), f2bf(v[2]), f2bf(v[3]) };
        ((s4*)out)[t] = s;
    }
}

// ---------- counting sort by dst ----------
__global__ void hist_kernel(const int* __restrict__ ei, int* __restrict__ hist) {
    const int stride = gridDim.x * blockDim.x;
    for (int e = blockIdx.x * blockDim.x + threadIdx.x; e < NE; e += stride)
        atomicAdd(&hist[ei[NE + e]], 1);
}

// 250 blocks x 256 threads, chunk of 200 nodes each
__global__ void scan1_kernel(const int* __restrict__ hist, int* __restrict__ off,
                             int* __restrict__ csum) {
    __shared__ int s[256];
    const int b = blockIdx.x, t = threadIdx.x;
    const int idx = b * 200 + t;
    int v = (t < 200) ? hist[idx] : 0;
    s[t] = v;
    __syncthreads();
    for (int d = 1; d < 256; d <<= 1) {
        int x = (t >= d) ? s[t - d] : 0;
        __syncthreads();
        s[t] += x;
        __syncthreads();
    }
    if (t < 200) off[idx] = s[t] - v;   // exclusive within chunk
    if (t == 255) csum[b] = s[255];
}

__global__ void scan2_kernel(int* __restrict__ csum) {   // 1 block, 256 threads
    __shared__ int s[256];
    const int t = threadIdx.x;
    int v = (t < 250) ? csum[t] : 0;
    s[t] = v;
    __syncthreads();
    for (int d = 1; d < 256; d <<= 1) {
        int x = (t >= d) ? s[t - d] : 0;
        __syncthreads();
        s[t] += x;
        __syncthreads();
    }
    if (t < 250) csum[t] = s[t] - v;    // exclusive over chunks
}

__global__ void scan3_kernel(int* __restrict__ off, const int* __restrict__ csum,
                             int* __restrict__ pos) {
    const int b = blockIdx.x, t = threadIdx.x;
    if (t < 200) {
        const int idx = b * 200 + t;
        const int o = off[idx] + csum[b];
        off[idx] = o;
        pos[idx] = o;
    }
    if (b == 0 && t == 0) off[NN] = NE;
}

__global__ void scatter_kernel(const int* __restrict__ ei, int* __restrict__ pos,
                               int* __restrict__ perm) {
    const int stride = gridDim.x * blockDim.x;
    for (int e = blockIdx.x * blockDim.x + threadIdx.x; e < NE; e += stride) {
        const int d = ei[NE + e];
        const int p = atomicAdd(&pos[d], 1);
        perm[p] = e;
    }
}

// ---------- edge kernel: message MLP + segmented-sum scatter ----------
// tile = 64 sorted edges x 128 out, K1 = 320 (128 src nf | 128 dst nf | 32 ef | cs,cd,30x0)
__global__ __launch_bounds__(256, 2)
void edge_kernel(const short* __restrict__ nf16, const int* __restrict__ ei,
                 const float* __restrict__ ef, const float* __restrict__ coord,
                 const int* __restrict__ perm,
                 const short* __restrict__ W1p, const float* __restrict__ mb1,
                 const short* __restrict__ W2p, const float* __restrict__ mb2,
                 float* __restrict__ agg) {
    constexpr int K1 = 320, LDA = 328, LDH = 136, LDM = 132;
    __shared__ short A[64 * LDA];   // aliased as M (f32 [64][132] = 33,792B <= 41,984B)
    __shared__ short H[64 * LDH];
    __shared__ int sdst[64];
    float* M = (float*)A;

    const int tid = threadIdx.x;
    const int ebase = blockIdx.x * 64;

    // ---- stage A-tile: 4 threads per edge-row (edges in dst-sorted order) ----
    {
        const int r = tid >> 2, q = tid & 3;
        const int e = perm[ebase + r];
        const int s = ei[e];
        const int d = ei[NE + e];
        if (q == 0) sdst[r] = d;
        short* Ar = A + r * LDA;
        const short* ps = nf16 + (long)s * HID + q * 32;
        const short* pd = nf16 + (long)d * HID + q * 32;
#pragma unroll
        for (int j = 0; j < 4; ++j) {
            *(bf8*)(Ar + q * 32 + j * 8) = *(const bf8*)(ps + j * 8);
            *(bf8*)(Ar + 128 + q * 32 + j * 8) = *(const bf8*)(pd + j * 8);
        }
        const float* pe = ef + (long)e * 32 + q * 8;
        f4 v0 = *(const f4*)pe, v1 = *(const f4*)(pe + 4);
        bf8 w = { f2bf(v0[0]), f2bf(v0[1]), f2bf(v0[2]), f2bf(v0[3]),
                  f2bf(v1[0]), f2bf(v1[1]), f2bf(v1[2]), f2bf(v1[3]) };
        *(bf8*)(Ar + 256 + q * 8) = w;
        bf8 z = {};
        *(bf8*)(Ar + 288 + q * 8) = z;
        if (q == 0) { Ar[288] = f2bf(coord[s]); Ar[289] = f2bf(coord[d]); }
    }
    __syncthreads();

    const int lane = tid & 63, wv = tid >> 6;
    const int g = lane >> 4, i16 = lane & 15, wc = wv * 32;

    // ---- layer 1: [64,320] @ [320,128] ----
    f4 acc[4][2] = {};
#pragma unroll
    for (int ks = 0; ks < K1 / 32; ++ks) {
        const int kb = ks * 32 + g * 8;
        bf8 b0 = *(const bf8*)(W1p + (wc + i16) * K1 + kb);
        bf8 b1 = *(const bf8*)(W1p + (wc + 16 + i16) * K1 + kb);
#pragma unroll
        for (int m = 0; m < 4; ++m) {
            bf8 a = *(const bf8*)(A + (m * 16 + i16) * LDA + kb);
            acc[m][0] = MFMA(a, b0, acc[m][0]);
            acc[m][1] = MFMA(a, b1, acc[m][1]);
        }
    }
    // silu -> H (bf16)
    {
        const float c0 = mb1[wc + i16], c1 = mb1[wc + 16 + i16];
#pragma unroll
        for (int m = 0; m < 4; ++m)
#pragma unroll
            for (int n = 0; n < 2; ++n)
#pragma unroll
                for (int i = 0; i < 4; ++i) {
                    const int row = m * 16 + g * 4 + i;
                    const int col = wc + n * 16 + i16;
                    float x = acc[m][n][i] + (n ? c1 : c0);
                    float h = x / (1.f + __expf(-x));
                    H[row * LDH + col] = f2bf(h);
                }
    }
    __syncthreads();   // all A reads done; H ready

    // ---- layer 2: [64,128] @ [128,128] ----
    f4 acc2[4][2] = {};
#pragma unroll
    for (int ks = 0; ks < 4; ++ks) {
        const int kb = ks * 32 + g * 8;
        bf8 b0 = *(const bf8*)(W2p + (wc + i16) * 128 + kb);
        bf8 b1 = *(const bf8*)(W2p + (wc + 16 + i16) * 128 + kb);
#pragma unroll
        for (int m = 0; m < 4; ++m) {
            bf8 a = *(const bf8*)(H + (m * 16 + i16) * LDH + kb);
            acc2[m][0] = MFMA(a, b0, acc2[m][0]);
            acc2[m][1] = MFMA(a, b1, acc2[m][1]);
        }
    }
    // messages -> M (aliases A; safe: all A reads finished before the H sync above)
    {
        const float c0 = mb2[wc + i16], c1 = mb2[wc + 16 + i16];
#pragma unroll
        for (int m = 0; m < 4; ++m)
#pragma unroll
            for (int n = 0; n < 2; ++n)
#pragma unroll
                for (int i = 0; i < 4; ++i) {
                    const int row = m * 16 + g * 4 + i;
                    const int col = wc + n * 16 + i16;
                    M[row * LDM + col] = acc2[m][n][i] + (n ? c1 : c0);
                }
    }
    __syncthreads();

    // ---- segmented reduction over sorted rows: 2 threads per column ----
    {
        const int col = tid >> 1, half = tid & 1;
        const int r0 = half * 32, r1 = r0 + 32;
        float run = 0.f;
#pragma unroll
        for (int r = r0; r < r1; ++r) {
            run += M[r * LDM + col];
            const bool last = (r == r1 - 1) || (sdst[r + 1] != sdst[r]);
            if (last) {
                atomicAdd(agg + (long)sdst[r] * HID + col, run);
                run = 0.f;
            }
        }
    }
}

// ---------- node kernel: update MLP + residual + LayerNorm ----------
__global__ __launch_bounds__(256, 2)
void node_kernel(const float* __restrict__ nf, const short* __restrict__ nf16,
                 const float* __restrict__ agg, const float* __restrict__ coord,
                 const short* __restrict__ U1p, const float* __restrict__ ub1,
                 const short* __restrict__ U2p, const float* __restrict__ ub2,
                 const float* __restrict__ gamma, const float* __restrict__ beta,
                 float* __restrict__ out) {
    constexpr int K1 = 288, LDA = 296, LDH = 136, LDX = 132;
    __shared__ short A[64 * LDA];   // later aliased as X (f32 [64][132] = 33792B)
    __shared__ short H[64 * LDH];
    float* X = (float*)A;

    const int tid = threadIdx.x;
    const int nbase = blockIdx.x * 64;

    {
        const int r = tid >> 2, q = tid & 3;
        const int node = nbase + r;
        short* Ar = A + r * LDA;
        bf8 z = {};
        if (node < NN) {
            const short* pn = nf16 + (long)node * HID + q * 32;
#pragma unroll
            for (int j = 0; j < 4; ++j)
                *(bf8*)(Ar + q * 32 + j * 8) = *(const bf8*)(pn + j * 8);
            const float* pa = agg + (long)node * HID + q * 32;
#pragma unroll
            for (int j = 0; j < 4; ++j) {
                f4 v0 = *(const f4*)(pa + j * 8);
                f4 v1 = *(const f4*)(pa + j * 8 + 4);
                bf8 w = { f2bf(v0[0]), f2bf(v0[1]), f2bf(v0[2]), f2bf(v0[3]),
                          f2bf(v1[0]), f2bf(v1[1]), f2bf(v1[2]), f2bf(v1[3]) };
                *(bf8*)(Ar + 128 + q * 32 + j * 8) = w;
            }
            *(bf8*)(Ar + 256 + q * 8) = z;
            if (q == 0) Ar[256] = f2bf(coord[node]);
        } else {
#pragma unroll
            for (int j = 0; j < 4; ++j) {
                *(bf8*)(Ar + q * 32 + j * 8) = z;
                *(bf8*)(Ar + 128 + q * 32 + j * 8) = z;
            }
            *(bf8*)(Ar + 256 + q * 8) = z;
        }
    }
    __syncthreads();

    const int lane = tid & 63, wv = tid >> 6;
    const int g = lane >> 4, i16 = lane & 15, wc = wv * 32;

    f4 acc[4][2] = {};
#pragma unroll
    for (int ks = 0; ks < K1 / 32; ++ks) {
        const int kb = ks * 32 + g * 8;
        bf8 b0 = *(const bf8*)(U1p + (wc + i16) * K1 + kb);
        bf8 b1 = *(const bf8*)(U1p + (wc + 16 + i16) * K1 + kb);
#pragma unroll
        for (int m = 0; m < 4; ++m) {
            bf8 a = *(const bf8*)(A + (m * 16 + i16) * LDA + kb);
            acc[m][0] = MFMA(a, b0, acc[m][0]);
            acc[m][1] = MFMA(a, b1, acc[m][1]);
        }
    }
    {
        const float c0 = ub1[wc + i16], c1 = ub1[wc + 16 + i16];
#pragma unroll
        for (int m = 0; m < 4; ++m)
#pragma unroll
            for (int n = 0; n < 2; ++n)
#pragma unroll
                for (int i = 0; i < 4; ++i) {
                    const int row = m * 16 + g * 4 + i;
                    const int col = wc + n * 16 + i16;
                    float x = acc[m][n][i] + (n ? c1 : c0);
                    float h = x / (1.f + __expf(-x));
                    H[row * LDH + col] = f2bf(h);
                }
    }
    __syncthreads();

    f4 acc2[4][2] = {};
#pragma unroll
    for (int ks = 0; ks < 4; ++ks) {
        const int kb = ks * 32 + g * 8;
        bf8 b0 = *(const bf8*)(U2p + (wc + i16) * 128 + kb);
        bf8 b1 = *(const bf8*)(U2p + (wc + 16 + i16) * 128 + kb);
#pragma unroll
        for (int m = 0; m < 4; ++m) {
            bf8 a = *(const bf8*)(H + (m * 16 + i16) * LDH + kb);
            acc2[m][0] = MFMA(a, b0, acc2[m][0]);
            acc2[m][1] = MFMA(a, b1, acc2[m][1]);
        }
    }
    {
        const float c0 = ub2[wc + i16], c1 = ub2[wc + 16 + i16];
#pragma unroll
        for (int m = 0; m < 4; ++m)
#pragma unroll
            for (int n = 0; n < 2; ++n)
#pragma unroll
                for (int i = 0; i < 4; ++i) {
                    const int row = m * 16 + g * 4 + i;
                    const int node = nbase + row;
                    const int col = wc + n * 16 + i16;
                    float v = acc2[m][n][i] + (n ? c1 : c0);
                    float base = (node < NN) ? nf[(long)node * HID + col] : 0.f;
                    X[row * LDX + col] = base + v;
                }
    }
    __syncthreads();

    {
        const int r = tid >> 2, q = tid & 3;
        const int node = nbase + r;
        float s = 0.f;
#pragma unroll
        for (int j = 0; j < 32; ++j) s += X[r * LDX + q * 32 + j];
        s += __shfl_xor(s, 1);
        s += __shfl_xor(s, 2);
        const float mu = s * (1.f / 128.f);
        float vv = 0.f;
#pragma unroll
        for (int j = 0; j < 32; ++j) {
            float d = X[r * LDX + q * 32 + j] - mu;
            vv += d * d;
        }
        vv += __shfl_xor(vv, 1);
        vv += __shfl_xor(vv, 2);
        const float rstd = rsqrtf(vv * (1.f / 128.f) + 1e-5f);
        if (node < NN) {
#pragma unroll
            for (int j = 0; j < 32; ++j) {
                const int c = q * 32 + j;
                out[(long)node * HID + c] = (X[r * LDX + c] - mu) * rstd * gamma[c] + beta[c];
            }
        }
    }
}

extern "C" void kernel_launch(void* const* d_in, const int* in_sizes, int n_in,
                              void* d_out, int out_size, void* d_ws, size_t ws_size,
                              hipStream_t stream) {
    const float* nf    = (const float*)d_in[0];
    const int*   ei    = (const int*)d_in[1];
    const float* ef    = (const float*)d_in[2];
    const float* coord = (const float*)d_in[3];
    const float* mW1 = (const float*)d_in[4];
    const float* mb1 = (const float*)d_in[5];
    const float* mW2 = (const float*)d_in[6];
    const float* mb2 = (const float*)d_in[7];
    const float* uW1 = (const float*)d_in[8];
    const float* ub1 = (const float*)d_in[9];
    const float* uW2 = (const float*)d_in[10];
    const float* ub2 = (const float*)d_in[11];
    const float* gamma = (const float*)d_in[12];
    const float* beta  = (const float*)d_in[13];
    float* out = (float*)d_out;

    char* ws = (char*)d_ws;
    float* agg  = (float*)ws;
    short* nf16 = (short*)(ws + 25600000);
    short* W1p  = (short*)(ws + 38400000);
    short* W2p  = W1p + 128 * 320;
    short* U1p  = W2p + 128 * 128;
    short* U2p  = U1p + 128 * 288;
    int* hist = (int*)(ws + 38621184);
    int* off  = (int*)(ws + 38821184);
    int* pos  = (int*)(ws + 39021188);
    int* csum = (int*)(ws + 39221188);
    int* perm = (int*)(ws + 39222212);

    hipMemsetAsync(agg, 0, (size_t)NN * HID * sizeof(float), stream);
    hipMemsetAsync(hist, 0, (size_t)NN * sizeof(int), stream);
    pack_weights_kernel<<<64, 256, 0, stream>>>(mW1, mW2, uW1, uW2, W1p, W2p, U1p, U2p);
    cvt_nf_kernel<<<1024, 256, 0, stream>>>(nf, nf16, NN * HID / 4);
    hist_kernel<<<1024, 256, 0, stream>>>(ei, hist);
    scan1_kernel<<<250, 256, 0, stream>>>(hist, off, csum);
    scan2_kernel<<<1, 256, 0, stream>>>(csum);
    scan3_kernel<<<250, 256, 0, stream>>>(off, csum, pos);
    scatter_kernel<<<1024, 256, 0, stream>>>(ei, pos, perm);
    edge_kernel<<<NE / 64, 256, 0, stream>>>(nf16, ei, ef, coord, perm,
                                             W1p, mb1, W2p, mb2, agg);
    node_kernel<<<(NN + 63) / 64, 256, 0, stream>>>(nf, nf16, agg, coord,
                                                    U1p, ub1, U2p, ub2, gamma, beta, out);
}

// Round 3
// 262.857 us; speedup vs baseline: 1.5142x; 1.3407x over previous
//
#include <hip/hip_runtime.h>

#define NN 50000
#define NE 640000
#define HID 128

// ---- workspace layout (bytes) ----
// agg   f32 [NN*128]   @ 0            25,600,000
// Wpre  bf16[256*128]  @ 25,600,000       65,536
// W1e   bf16[128*32]   @ 25,665,536        8,192
// W2p   bf16[128*128]  @ 25,673,728       32,768
// U1p   bf16[128*288]  @ 25,706,496       73,728
// U2p   bf16[128*128]  @ 25,780,224       32,768
// Waux  f32 [256]      @ 25,812,992        1,024
// Baux  f32 [256]      @ 25,814,016        1,024
// hist  int [50000]    @ 25,815,040      200,000
// pos   int [50000]    @ 26,015,040      200,000
// csum  int [256]      @ 26,215,040        1,024
// perm  int [640000]   @ 26,216,064    2,560,000
// end ~28.8 MB.  Ppre bf16[NN*256] (25.6MB) lives in d_out (dead until node_kernel).

typedef __attribute__((ext_vector_type(8))) short bf8;  // 8 bf16 = 16B
typedef __attribute__((ext_vector_type(4))) float f4;

#define MFMA(a, b, c) __builtin_amdgcn_mfma_f32_16x16x32_bf16(a, b, c, 0, 0, 0)

__device__ __forceinline__ short f2bf(float f) {
    union { float f; unsigned u; } v; v.f = f;
    unsigned r = v.u + 0x7FFFu + ((v.u >> 16) & 1u);
    return (short)(r >> 16);
}
__device__ __forceinline__ float bf2f(short s) {
    union { unsigned u; float f; } v; v.u = ((unsigned)(unsigned short)s) << 16;
    return v.f;
}
__device__ __forceinline__ float silu(float x) {
    return x * __builtin_amdgcn_rcpf(1.f + __expf(-x));
}

// ---------- pack weights ----------
__global__ void pack_weights_kernel(const float* __restrict__ mW1, const float* __restrict__ mb1,
                                    const float* __restrict__ mW2,
                                    const float* __restrict__ uW1, const float* __restrict__ uW2,
                                    short* __restrict__ Wpre, short* __restrict__ W1e,
                                    short* __restrict__ W2p, short* __restrict__ U1p,
                                    short* __restrict__ U2p,
                                    float* __restrict__ Waux, float* __restrict__ Baux) {
    const int stride = gridDim.x * blockDim.x;
    const int idx = blockIdx.x * blockDim.x + threadIdx.x;
    // Wpre[cc][k]: cc<128 -> mW1[k][cc] (src part); cc>=128 -> mW1[128+k][cc-128] (dst part)
    for (int t = idx; t < 256 * 128; t += stride) {
        int cc = t / 128, k = t % 128;
        float v = (cc < 128) ? mW1[k * 128 + cc] : mW1[(128 + k) * 128 + (cc - 128)];
        Wpre[t] = f2bf(v);
    }
    // W1e[c][k] = mW1[256+k][c], k in [0,32)
    for (int t = idx; t < 128 * 32; t += stride) {
        int c = t / 32, k = t % 32;
        W1e[t] = f2bf(mW1[(256 + k) * 128 + c]);
    }
    for (int t = idx; t < 128 * 128; t += stride)
        W2p[t] = f2bf(mW2[(t % 128) * 128 + (t / 128)]);
    for (int t = idx; t < 128 * 288; t += stride) {
        int n = t / 288, k = t % 288;
        U1p[t] = (k < 257) ? f2bf(uW1[k * 128 + n]) : (short)0;
    }
    for (int t = idx; t < 128 * 128; t += stride)
        U2p[t] = f2bf(uW2[(t % 128) * 128 + (t / 128)]);
    for (int t = idx; t < 256; t += stride) {
        Waux[t] = (t < 128) ? mW1[288 * 128 + t] : mW1[289 * 128 + (t - 128)];
        Baux[t] = (t < 128) ? 0.f : mb1[t - 128];
    }
}

// ---------- node precompute: Ppre[n] = [nf@W1src + c*w288 | nf@W1dst + c*w289 + mb1] ----------
__global__ __launch_bounds__(256, 3)
void node_pre_kernel(const float* __restrict__ nf, const float* __restrict__ coord,
                     const short* __restrict__ Wpre, const float* __restrict__ Waux,
                     const float* __restrict__ Baux, short* __restrict__ Ppre) {
    __shared__ short SH[64 * 264];     // A [64][136] then P [64][264] (phase-disjoint)
    __shared__ float scoord[64];
    short* A = SH;
    short* P = SH;
    const int tid = threadIdx.x;
    const int nbase = blockIdx.x * 64;

    {   // stage nf -> bf16 A
        const int r = tid >> 2, q = tid & 3;
        const int node = nbase + r;
        short* Ar = A + r * 136 + q * 32;
        if (node < NN) {
            const float* p = nf + (long)node * HID + q * 32;
#pragma unroll
            for (int j = 0; j < 4; ++j) {
                f4 v0 = *(const f4*)(p + j * 8), v1 = *(const f4*)(p + j * 8 + 4);
                bf8 w = { f2bf(v0[0]), f2bf(v0[1]), f2bf(v0[2]), f2bf(v0[3]),
                          f2bf(v1[0]), f2bf(v1[1]), f2bf(v1[2]), f2bf(v1[3]) };
                *(bf8*)(Ar + j * 8) = w;
            }
            if (q == 0) scoord[r] = coord[node];
        } else {
            bf8 z = {};
#pragma unroll
            for (int j = 0; j < 4; ++j) *(bf8*)(Ar + j * 8) = z;
            if (q == 0) scoord[r] = 0.f;
        }
    }
    __syncthreads();

    const int lane = tid & 63, wv = tid >> 6;
    const int g = lane >> 4, i16 = lane & 15, wc = wv * 64;

    f4 acc[4][4] = {};
#pragma unroll
    for (int ks = 0; ks < 4; ++ks) {
        const int kb = ks * 32 + g * 8;
        bf8 b[4];
#pragma unroll
        for (int n = 0; n < 4; ++n)
            b[n] = *(const bf8*)(Wpre + (wc + n * 16 + i16) * 128 + kb);
#pragma unroll
        for (int m = 0; m < 4; ++m) {
            bf8 a = *(const bf8*)(A + (m * 16 + i16) * 136 + kb);
#pragma unroll
            for (int n = 0; n < 4; ++n) acc[m][n] = MFMA(a, b[n], acc[m][n]);
        }
    }
    __syncthreads();   // A dead -> P writable

#pragma unroll
    for (int n = 0; n < 4; ++n) {
        const int cc = wc + n * 16 + i16;
        const float wa = Waux[cc], ba = Baux[cc];
#pragma unroll
        for (int m = 0; m < 4; ++m)
#pragma unroll
            for (int i = 0; i < 4; ++i) {
                const int row = m * 16 + g * 4 + i;
                P[row * 264 + cc] = f2bf(acc[m][n][i] + scoord[row] * wa + ba);
            }
    }
    __syncthreads();

    {   // coalesced store
        const int r = tid >> 2, q = tid & 3;
        const int node = nbase + r;
        if (node < NN) {
#pragma unroll
            for (int j = 0; j < 8; ++j)
                *(bf8*)(Ppre + (long)node * 256 + q * 64 + j * 8) =
                    *(const bf8*)(P + r * 264 + q * 64 + j * 8);
        }
    }
}

// ---------- counting sort by dst ----------
__global__ void hist_kernel(const int* __restrict__ ei, int* __restrict__ hist) {
    const int stride = gridDim.x * blockDim.x;
    for (int e = blockIdx.x * blockDim.x + threadIdx.x; e < NE; e += stride)
        atomicAdd(&hist[ei[NE + e]], 1);
}

__global__ void scan1_kernel(const int* __restrict__ hist, int* __restrict__ pos,
                             int* __restrict__ csum) {
    __shared__ int s[256];
    const int b = blockIdx.x, t = threadIdx.x;
    const int idx = b * 200 + t;
    int v = (t < 200) ? hist[idx] : 0;
    s[t] = v;
    __syncthreads();
    for (int d = 1; d < 256; d <<= 1) {
        int x = (t >= d) ? s[t - d] : 0;
        __syncthreads();
        s[t] += x;
        __syncthreads();
    }
    if (t < 200) pos[idx] = s[t] - v;
    if (t == 255) csum[b] = s[255];
}

__global__ void scan2_kernel(int* __restrict__ csum) {
    __shared__ int s[256];
    const int t = threadIdx.x;
    int v = (t < 250) ? csum[t] : 0;
    s[t] = v;
    __syncthreads();
    for (int d = 1; d < 256; d <<= 1) {
        int x = (t >= d) ? s[t - d] : 0;
        __syncthreads();
        s[t] += x;
        __syncthreads();
    }
    if (t < 250) csum[t] = s[t] - v;
}

__global__ void scan3_kernel(int* __restrict__ pos, const int* __restrict__ csum) {
    const int b = blockIdx.x, t = threadIdx.x;
    if (t < 200) pos[b * 200 + t] += csum[b];
}

__global__ void scatter_kernel(const int* __restrict__ ei, int* __restrict__ pos,
                               int* __restrict__ perm) {
    const int stride = gridDim.x * blockDim.x;
    for (int e = blockIdx.x * blockDim.x + threadIdx.x; e < NE; e += stride) {
        const int d = ei[NE + e];
        const int p = atomicAdd(&pos[d], 1);
        perm[p] = e;
    }
}

// ---------- edge kernel: ef-MFMA + gathered Ppre + silu + layer2 + seg-reduce ----------
__global__ __launch_bounds__(256, 4)
void edge_kernel(const int* __restrict__ ei, const float* __restrict__ ef,
                 const int* __restrict__ perm, const short* __restrict__ Ppre,
                 const short* __restrict__ W1e, const short* __restrict__ W2p,
                 const float* __restrict__ mb2, float* __restrict__ agg) {
    constexpr int LDEF = 40, LDH = 136, LDM = 132;
    __shared__ float R[64 * 132];                 // 33,792 B — A_ef / H / M phase-disjoint
    __shared__ int sdst[64], ssrc[64];
    short* Aef = (short*)R;
    short* H = (short*)R;
    float* M = R;

    const int tid = threadIdx.x;
    const int bid = blockIdx.x;
    const int ebase = ((bid & 7) * 1250 + (bid >> 3)) * 64;   // XCD-chunked swizzle (10000 = 8*1250)

    {   // stage ef tile (+ edge endpoints)
        const int r = tid >> 2, q = tid & 3;
        const int e = perm[ebase + r];
        if (q == 0) { ssrc[r] = ei[e]; sdst[r] = ei[NE + e]; }
        const float* pe = ef + (long)e * 32 + q * 8;
        f4 v0 = *(const f4*)pe, v1 = *(const f4*)(pe + 4);
        bf8 w = { f2bf(v0[0]), f2bf(v0[1]), f2bf(v0[2]), f2bf(v0[3]),
                  f2bf(v1[0]), f2bf(v1[1]), f2bf(v1[2]), f2bf(v1[3]) };
        *(bf8*)(Aef + r * LDEF + q * 8) = w;
    }
    __syncthreads();

    const int lane = tid & 63, wv = tid >> 6;
    const int g = lane >> 4, i16 = lane & 15, wc = wv * 32;

    // layer-1 ef part: [64,32] @ [32,128]
    f4 acc[4][2] = {};
    {
        bf8 b0 = *(const bf8*)(W1e + (wc + i16) * 32 + g * 8);
        bf8 b1 = *(const bf8*)(W1e + (wc + 16 + i16) * 32 + g * 8);
#pragma unroll
        for (int m = 0; m < 4; ++m) {
            bf8 a = *(const bf8*)(Aef + (m * 16 + i16) * LDEF + g * 8);
            acc[m][0] = MFMA(a, b0, acc[m][0]);
            acc[m][1] = MFMA(a, b1, acc[m][1]);
        }
    }
    __syncthreads();   // Aef dead

    // partial -> H (bf16)
#pragma unroll
    for (int m = 0; m < 4; ++m)
#pragma unroll
        for (int n = 0; n < 2; ++n)
#pragma unroll
            for (int i = 0; i < 4; ++i)
                H[(m * 16 + g * 4 + i) * LDH + wc + n * 16 + i16] = f2bf(acc[m][n][i]);
    __syncthreads();

    {   // gather Ppre[src], Ppre[dst] + silu (in place)
        const int r = tid >> 2, q = tid & 3;
        const short* p1 = Ppre + (long)ssrc[r] * 256 + q * 32;
        const short* p2 = Ppre + (long)sdst[r] * 256 + 128 + q * 32;
        bf8 a1[4], a2[4];
#pragma unroll
        for (int j = 0; j < 4; ++j) { a1[j] = *(const bf8*)(p1 + j * 8); }
#pragma unroll
        for (int j = 0; j < 4; ++j) { a2[j] = *(const bf8*)(p2 + j * 8); }
        short* Hr = H + r * LDH + q * 32;
#pragma unroll
        for (int j = 0; j < 4; ++j)
#pragma unroll
            for (int t = 0; t < 8; ++t) {
                float x = bf2f(Hr[j * 8 + t]) + bf2f(a1[j][t]) + bf2f(a2[j][t]);
                Hr[j * 8 + t] = f2bf(silu(x));
            }
    }
    __syncthreads();

    // layer 2: [64,128] @ [128,128]
    f4 acc2[4][2] = {};
#pragma unroll
    for (int ks = 0; ks < 4; ++ks) {
        const int kb = ks * 32 + g * 8;
        bf8 b0 = *(const bf8*)(W2p + (wc + i16) * 128 + kb);
        bf8 b1 = *(const bf8*)(W2p + (wc + 16 + i16) * 128 + kb);
#pragma unroll
        for (int m = 0; m < 4; ++m) {
            bf8 a = *(const bf8*)(H + (m * 16 + i16) * LDH + kb);
            acc2[m][0] = MFMA(a, b0, acc2[m][0]);
            acc2[m][1] = MFMA(a, b1, acc2[m][1]);
        }
    }
    __syncthreads();   // H dead

    {   // messages -> M (f32)
        const float c0 = mb2[wc + i16], c1 = mb2[wc + 16 + i16];
#pragma unroll
        for (int m = 0; m < 4; ++m)
#pragma unroll
            for (int n = 0; n < 2; ++n)
#pragma unroll
                for (int i = 0; i < 4; ++i)
                    M[(m * 16 + g * 4 + i) * LDM + wc + n * 16 + i16] =
                        acc2[m][n][i] + (n ? c1 : c0);
    }
    __syncthreads();

    {   // segmented reduction over dst-sorted rows: 2 threads per column
        const int col = tid >> 1, half = tid & 1;
        const int r0 = half * 32, r1 = r0 + 32;
        float run = 0.f;
#pragma unroll
        for (int r = r0; r < r1; ++r) {
            run += M[r * LDM + col];
            const bool last = (r == r1 - 1) || (sdst[r + 1] != sdst[r]);
            if (last) {
                atomicAdd(agg + (long)sdst[r] * HID + col, run);
                run = 0.f;
            }
        }
    }
}

// ---------- node kernel: update MLP + residual + LayerNorm ----------
__global__ __launch_bounds__(256, 4)
void node_kernel(const float* __restrict__ nf, const float* __restrict__ agg,
                 const float* __restrict__ coord,
                 const short* __restrict__ U1p, const float* __restrict__ ub1,
                 const short* __restrict__ U2p, const float* __restrict__ ub2,
                 const float* __restrict__ gamma, const float* __restrict__ beta,
                 float* __restrict__ out) {
    constexpr int K1 = 288, LDA = 296, LDH = 136, LDX = 132;
    __shared__ short SH[64 * LDA];    // 37,888 B — A / H / X phase-disjoint
    short* A = SH;
    short* H = SH;
    float* X = (float*)SH;

    const int tid = threadIdx.x;
    const int nbase = blockIdx.x * 64;

    {   // stage [nf | agg | coord] as bf16
        const int r = tid >> 2, q = tid & 3;
        const int node = nbase + r;
        short* Ar = A + r * LDA;
        bf8 z = {};
        if (node < NN) {
            const float* pn = nf + (long)node * HID + q * 32;
            const float* pa = agg + (long)node * HID + q * 32;
#pragma unroll
            for (int j = 0; j < 4; ++j) {
                f4 v0 = *(const f4*)(pn + j * 8), v1 = *(const f4*)(pn + j * 8 + 4);
                bf8 w = { f2bf(v0[0]), f2bf(v0[1]), f2bf(v0[2]), f2bf(v0[3]),
                          f2bf(v1[0]), f2bf(v1[1]), f2bf(v1[2]), f2bf(v1[3]) };
                *(bf8*)(Ar + q * 32 + j * 8) = w;
            }
#pragma unroll
            for (int j = 0; j < 4; ++j) {
                f4 v0 = *(const f4*)(pa + j * 8), v1 = *(const f4*)(pa + j * 8 + 4);
                bf8 w = { f2bf(v0[0]), f2bf(v0[1]), f2bf(v0[2]), f2bf(v0[3]),
                          f2bf(v1[0]), f2bf(v1[1]), f2bf(v1[2]), f2bf(v1[3]) };
                *(bf8*)(Ar + 128 + q * 32 + j * 8) = w;
            }
            *(bf8*)(Ar + 256 + q * 8) = z;
            if (q == 0) Ar[256] = f2bf(coord[node]);
        } else {
#pragma unroll
            for (int j = 0; j < 4; ++j) {
                *(bf8*)(Ar + q * 32 + j * 8) = z;
                *(bf8*)(Ar + 128 + q * 32 + j * 8) = z;
            }
            *(bf8*)(Ar + 256 + q * 8) = z;
        }
    }
    __syncthreads();

    const int lane = tid & 63, wv = tid >> 6;
    const int g = lane >> 4, i16 = lane & 15, wc = wv * 32;

    f4 acc[4][2] = {};
#pragma unroll
    for (int ks = 0; ks < K1 / 32; ++ks) {
        const int kb = ks * 32 + g * 8;
        bf8 b0 = *(const bf8*)(U1p + (wc + i16) * K1 + kb);
        bf8 b1 = *(const bf8*)(U1p + (wc + 16 + i16) * K1 + kb);
#pragma unroll
        for (int m = 0; m < 4; ++m) {
            bf8 a = *(const bf8*)(A + (m * 16 + i16) * LDA + kb);
            acc[m][0] = MFMA(a, b0, acc[m][0]);
            acc[m][1] = MFMA(a, b1, acc[m][1]);
        }
    }
    __syncthreads();   // A dead

    {   // silu -> H
        const float c0 = ub1[wc + i16], c1 = ub1[wc + 16 + i16];
#pragma unroll
        for (int m = 0; m < 4; ++m)
#pragma unroll
            for (int n = 0; n < 2; ++n)
#pragma unroll
                for (int i = 0; i < 4; ++i) {
                    float x = acc[m][n][i] + (n ? c1 : c0);
                    H[(m * 16 + g * 4 + i) * LDH + wc + n * 16 + i16] = f2bf(silu(x));
                }
    }
    __syncthreads();

    f4 acc2[4][2] = {};
#pragma unroll
    for (int ks = 0; ks < 4; ++ks) {
        const int kb = ks * 32 + g * 8;
        bf8 b0 = *(const bf8*)(U2p + (wc + i16) * 128 + kb);
        bf8 b1 = *(const bf8*)(U2p + (wc + 16 + i16) * 128 + kb);
#pragma unroll
        for (int m = 0; m < 4; ++m) {
            bf8 a = *(const bf8*)(H + (m * 16 + i16) * LDH + kb);
            acc2[m][0] = MFMA(a, b0, acc2[m][0]);
            acc2[m][1] = MFMA(a, b1, acc2[m][1]);
        }
    }
    __syncthreads();   // H dead

    {   // X = nf + upd
        const float c0 = ub2[wc + i16], c1 = ub2[wc + 16 + i16];
#pragma unroll
        for (int m = 0; m < 4; ++m)
#pragma unroll
            for (int n = 0; n < 2; ++n)
#pragma unroll
                for (int i = 0; i < 4; ++i) {
                    const int row = m * 16 + g * 4 + i;
                    const int node = nbase + row;
                    const int col = wc + n * 16 + i16;
                    float v = acc2[m][n][i] + (n ? c1 : c0);
                    float base = (node < NN) ? nf[(long)node * HID + col] : 0.f;
                    X[row * LDX + col] = base + v;
                }
    }
    __syncthreads();

    {   // LayerNorm: 4 threads per row
        const int r = tid >> 2, q = tid & 3;
        const int node = nbase + r;
        float s = 0.f;
#pragma unroll
        for (int j = 0; j < 32; ++j) s += X[r * LDX + q * 32 + j];
        s += __shfl_xor(s, 1);
        s += __shfl_xor(s, 2);
        const float mu = s * (1.f / 128.f);
        float vv = 0.f;
#pragma unroll
        for (int j = 0; j < 32; ++j) {
            float d = X[r * LDX + q * 32 + j] - mu;
            vv += d * d;
        }
        vv += __shfl_xor(vv, 1);
        vv += __shfl_xor(vv, 2);
        const float rstd = rsqrtf(vv * (1.f / 128.f) + 1e-5f);
        if (node < NN) {
#pragma unroll
            for (int j = 0; j < 32; ++j) {
                const int c = q * 32 + j;
                out[(long)node * HID + c] = (X[r * LDX + c] - mu) * rstd * gamma[c] + beta[c];
            }
        }
    }
}

extern "C" void kernel_launch(void* const* d_in, const int* in_sizes, int n_in,
                              void* d_out, int out_size, void* d_ws, size_t ws_size,
                              hipStream_t stream) {
    const float* nf    = (const float*)d_in[0];
    const int*   ei    = (const int*)d_in[1];
    const float* ef    = (const float*)d_in[2];
    const float* coord = (const float*)d_in[3];
    const float* mW1 = (const float*)d_in[4];
    const float* mb1 = (const float*)d_in[5];
    const float* mW2 = (const float*)d_in[6];
    const float* mb2 = (const float*)d_in[7];
    const float* uW1 = (const float*)d_in[8];
    const float* ub1 = (const float*)d_in[9];
    const float* uW2 = (const float*)d_in[10];
    const float* ub2 = (const float*)d_in[11];
    const float* gamma = (const float*)d_in[12];
    const float* beta  = (const float*)d_in[13];
    float* out = (float*)d_out;

    char* ws = (char*)d_ws;
    float* agg  = (float*)ws;
    short* Wpre = (short*)(ws + 25600000);
    short* W1e  = (short*)(ws + 25665536);
    short* W2p  = (short*)(ws + 25673728);
    short* U1p  = (short*)(ws + 25706496);
    short* U2p  = (short*)(ws + 25780224);
    float* Waux = (float*)(ws + 25812992);
    float* Baux = (float*)(ws + 25814016);
    int* hist = (int*)(ws + 25815040);
    int* pos  = (int*)(ws + 26015040);
    int* csum = (int*)(ws + 26215040);
    int* perm = (int*)(ws + 26216064);
    short* Ppre = (short*)d_out;   // scratch until node_kernel overwrites d_out

    hipMemsetAsync(agg, 0, (size_t)NN * HID * sizeof(float), stream);
    hipMemsetAsync(hist, 0, (size_t)NN * sizeof(int), stream);
    pack_weights_kernel<<<64, 256, 0, stream>>>(mW1, mb1, mW2, uW1, uW2,
                                                Wpre, W1e, W2p, U1p, U2p, Waux, Baux);
    node_pre_kernel<<<(NN + 63) / 64, 256, 0, stream>>>(nf, coord, Wpre, Waux, Baux, Ppre);
    hist_kernel<<<1024, 256, 0, stream>>>(ei, hist);
    scan1_kernel<<<250, 256, 0, stream>>>(hist, pos, csum);
    scan2_kernel<<<1, 256, 0, stream>>>(csum);
    scan3_kernel<<<250, 256, 0, stream>>>(pos, csum);
    scatter_kernel<<<1024, 256, 0, stream>>>(ei, pos, perm);
    edge_kernel<<<NE / 64, 256, 0, stream>>>(ei, ef, perm, Ppre, W1e, W2p, mb2, agg);
    node_kernel<<<(NN + 63) / 64, 256, 0, stream>>>(nf, agg, coord,
                                                    U1p, ub1, U2p, ub2, gamma, beta, out);
}